// Round 7
// baseline (349.971 us; speedup 1.0000x reference)
//
#include <hip/hip_runtime.h>
#include <hip/hip_bf16.h>

// Fully-fused Swin shifted-window attention, MI355X gfx950.
// B=8, H=W=128, D=256, NHEAD=8, DK=32, WS=8, NH=NW=16, WSQ=64, SHIFT=4.
// fused_k: 1 block = 1 window, 1024 threads = 16 waves, 2 waves/head (M-split).
//   stage x,z -> LDS bf16 once; per wave (h,m): Q,K proj halves -> barrier ->
//   V^T proj (XOR-swizzled, overlays dead xs) -> QK^T (32x64) -> barrier ->
//   softmax -> P -> PV -> barrier -> att -> barrier -> O-GEMM -> f32 out.

typedef __bf16  bf16x8 __attribute__((ext_vector_type(8)));
typedef short   short8 __attribute__((ext_vector_type(8)));
typedef float   f32x4  __attribute__((ext_vector_type(4)));

#define SCALE_F 0.17677669529663687f

// LDS map (shorts):
//  [0,16896)      xs[64][264]; after barrier2: 8x V^T[32][64] (XOR-swizzled) at h*2048
//  [16896,33792)  zs[64][264]
//  [33792,74752)  8 per-head regions of 5120:
//     Q[64][40] @0, K[64][40] @2560; P[64][72] overlay @0; att[64][40] overlay @0
#define ZS   16896
#define WB   33792
#define WSZ  5120
#define LDS_TOT 74752   // shorts = 146 KiB

__device__ __forceinline__ short f2bs(float f){
    __hip_bfloat16 h = __float2bfloat16(f);
    return __builtin_bit_cast(short, h);
}
__device__ __forceinline__ short8 cvt8(float4 a, float4 b){
    short8 t;
    t[0]=f2bs(a.x); t[1]=f2bs(a.y); t[2]=f2bs(a.z); t[3]=f2bs(a.w);
    t[4]=f2bs(b.x); t[5]=f2bs(b.y); t[6]=f2bs(b.z); t[7]=f2bs(b.w);
    return t;
}
__device__ __forceinline__ int strip3(int r, int c){
    if (c == 0) return 0;
    if (c == 1) return (r < 4) ? 0 : 1;
    return (r < 4) ? 2 : 0;
}

// ---------------- prep: weight transpose->bf16 + ADD table ------------------
__global__ __launch_bounds__(256) void prep_k(const float* __restrict__ Wq,
                                              const float* __restrict__ Wkv,
                                              const float* __restrict__ Wo,
                                              const float* __restrict__ rel,
                                              short* __restrict__ Wqt,
                                              short* __restrict__ Wkvt,
                                              short* __restrict__ Wot,
                                              float* __restrict__ ADD){
    int i = blockIdx.x * 256 + threadIdx.x;
    if (i < 65536){
        int n = i >> 8, k = i & 255;
        Wqt[i] = f2bs(Wq[k * 256 + n]);
    } else if (i < 196608){
        int j = i - 65536;
        int n = j >> 8, k = j & 255;
        Wkvt[j] = f2bs(Wkv[k * 512 + n]);
    } else if (i < 262144){
        int j = i - 196608;
        int n = j >> 8, k = j & 255;
        Wot[j] = f2bs(Wo[k * 256 + n]);
    } else {
        int j = i - 262144;
        int k = j & 63, q = (j >> 6) & 63, head = (j >> 12) & 7, cls = j >> 15;
        int wiC = cls / 3, wjC = cls - wiC * 3;
        int qr = q >> 3, qc = q & 7, kr = k >> 3, kc = k & 7;
        int lq = strip3(qr, wiC) * 3 + strip3(qc, wjC);
        int lk = strip3(kr, wiC) * 3 + strip3(kc, wjC);
        float pe = rel[((qr - kr + 7) * 15 + (qc - kc + 7)) * 8 + head];
        ADD[j] = (lq != lk) ? -1e9f : pe;
    }
}

__global__ __launch_bounds__(1024, 4) void fused_k(
    const float* __restrict__ x, const float* __restrict__ z,
    const short* __restrict__ Wqt, const short* __restrict__ Wkvt,
    const short* __restrict__ Wot,
    const float* __restrict__ bq, const float* __restrict__ bkv,
    const float* __restrict__ bo,
    const float* __restrict__ ADD, float* __restrict__ out){
    __shared__ __align__(16) short lds[LDS_TOT];
    const int tid = threadIdx.x, w = tid >> 6, lane = tid & 63;
    const int l15 = lane & 15, g = lane >> 4;
    const int h = w >> 1, m = w & 1, r0 = m * 32;
    const int bx = blockIdx.x;
    const int wj = bx & 15, wi = (bx >> 4) & 15, b = bx >> 8;
    const int wiC = (wi > 13) ? wi - 13 : 0;
    const int wjC = (wj > 13) ? wj - 13 : 0;
    const f32x4 zero = {0.f,0.f,0.f,0.f};

    // ---- stage x,z windows -> LDS bf16 [64][264], read once from HBM ----
#pragma unroll
    for (int i=0;i<2;++i){
        const int u = tid + i*1024;
        const int p = u >> 5, c8 = u & 31;
        const int pr = ((wi << 3) + (p >> 3) + 4) & 127;
        const int pc = ((wj << 3) + (p & 7) + 4) & 127;
        const size_t gidx = ((((((size_t)b << 7) | pr) << 7) | pc) << 8) + c8*8;
        const float4* xp = reinterpret_cast<const float4*>(x + gidx);
        float4 a0 = xp[0], a1 = xp[1];
        *reinterpret_cast<short8*>(lds + p*264 + c8*8) = cvt8(a0, a1);
        const float4* zp = reinterpret_cast<const float4*>(z + gidx);
        float4 b0 = zp[0], b1 = zp[1];
        *reinterpret_cast<short8*>(lds + ZS + p*264 + c8*8) = cvt8(b0, b1);
    }
    __syncthreads();                                  // (1)

    short* R  = lds + WB + h*WSZ;     // per-head: Q @0 p40, K @2560 p40; P/att overlay
    short* VL = lds + h*2048;         // per-head V^T [32][64] swizzled (xs overlay)
    const int c0 = h*32;

    // ---- Q projection (rows r0..r0+31) ----
    {
        bf16x8 wf[8][2];
#pragma unroll
        for (int kt=0;kt<8;++kt)
#pragma unroll
            for (int nj=0;nj<2;++nj)
                wf[kt][nj] = *reinterpret_cast<const bf16x8*>(Wqt + (size_t)(c0 + nj*16 + l15)*256 + kt*32 + g*8);
        f32x4 acc[2][2];
#pragma unroll
        for (int mi=0;mi<2;++mi){ acc[mi][0]=zero; acc[mi][1]=zero; }
#pragma unroll
        for (int kt=0;kt<8;++kt){
            bf16x8 af[2];
#pragma unroll
            for (int mi=0;mi<2;++mi)
                af[mi] = *reinterpret_cast<const bf16x8*>(lds + (r0 + mi*16 + l15)*264 + kt*32 + g*8);
#pragma unroll
            for (int mi=0;mi<2;++mi)
#pragma unroll
                for (int nj=0;nj<2;++nj)
                    acc[mi][nj] = __builtin_amdgcn_mfma_f32_16x16x32_bf16(af[mi], wf[kt][nj], acc[mi][nj], 0,0,0);
        }
#pragma unroll
        for (int nj=0;nj<2;++nj){
            float bv = bq[c0 + nj*16 + l15];
#pragma unroll
            for (int mi=0;mi<2;++mi)
#pragma unroll
                for (int r=0;r<4;++r)
                    R[(r0 + mi*16 + g*4 + r)*40 + nj*16 + l15] = f2bs(acc[mi][nj][r] + bv);
        }
    }
    // ---- K projection (keys r0..r0+31) ----
    {
        bf16x8 wf[8][2];
#pragma unroll
        for (int kt=0;kt<8;++kt)
#pragma unroll
            for (int nj=0;nj<2;++nj)
                wf[kt][nj] = *reinterpret_cast<const bf16x8*>(Wkvt + (size_t)(c0 + nj*16 + l15)*256 + kt*32 + g*8);
        f32x4 acc[2][2];
#pragma unroll
        for (int mi=0;mi<2;++mi){ acc[mi][0]=zero; acc[mi][1]=zero; }
#pragma unroll
        for (int kt=0;kt<8;++kt){
            bf16x8 af[2];
#pragma unroll
            for (int mi=0;mi<2;++mi)
                af[mi] = *reinterpret_cast<const bf16x8*>(lds + ZS + (r0 + mi*16 + l15)*264 + kt*32 + g*8);
#pragma unroll
            for (int mi=0;mi<2;++mi)
#pragma unroll
                for (int nj=0;nj<2;++nj)
                    acc[mi][nj] = __builtin_amdgcn_mfma_f32_16x16x32_bf16(af[mi], wf[kt][nj], acc[mi][nj], 0,0,0);
        }
#pragma unroll
        for (int nj=0;nj<2;++nj){
            float bv = bkv[c0 + nj*16 + l15];
#pragma unroll
            for (int mi=0;mi<2;++mi)
#pragma unroll
                for (int r=0;r<4;++r)
                    R[2560 + (r0 + mi*16 + g*4 + r)*40 + nj*16 + l15] = f2bs(acc[mi][nj][r] + bv);
        }
    }
    __syncthreads();                                  // (2) xs dead -> V^T overlay

    // ---- V projection -> VL[col][pix] pitch 64, XOR-swizzled (pixels r0..) ----
    {
        bf16x8 wf[8][2];
#pragma unroll
        for (int kt=0;kt<8;++kt)
#pragma unroll
            for (int nj=0;nj<2;++nj)
                wf[kt][nj] = *reinterpret_cast<const bf16x8*>(Wkvt + (size_t)(256 + c0 + nj*16 + l15)*256 + kt*32 + g*8);
        f32x4 acc[2][2];
#pragma unroll
        for (int mi=0;mi<2;++mi){ acc[mi][0]=zero; acc[mi][1]=zero; }
#pragma unroll
        for (int kt=0;kt<8;++kt){
            bf16x8 af[2];
#pragma unroll
            for (int mi=0;mi<2;++mi)
                af[mi] = *reinterpret_cast<const bf16x8*>(lds + ZS + (r0 + mi*16 + l15)*264 + kt*32 + g*8);
#pragma unroll
            for (int mi=0;mi<2;++mi)
#pragma unroll
                for (int nj=0;nj<2;++nj)
                    acc[mi][nj] = __builtin_amdgcn_mfma_f32_16x16x32_bf16(af[mi], wf[kt][nj], acc[mi][nj], 0,0,0);
        }
        const int sw = (l15 & 7) << 3;
#pragma unroll
        for (int nj=0;nj<2;++nj){
            float bv = bkv[256 + c0 + nj*16 + l15];
            const int colb = (nj*16 + l15) * 64;
#pragma unroll
            for (int mi=0;mi<2;++mi)
#pragma unroll
                for (int r=0;r<4;++r)
                    VL[(colb + r0 + mi*16 + g*4 + r) ^ sw] = f2bs(acc[mi][nj][r] + bv);
        }
    }

    // ---- QK^T: rows r0..r0+31 x all 64 keys ----
    bf16x8 aq[2], bk[4];
#pragma unroll
    for (int mi=0;mi<2;++mi) aq[mi] = *reinterpret_cast<const bf16x8*>(R + (r0 + mi*16 + l15)*40 + g*8);
#pragma unroll
    for (int ni=0;ni<4;++ni) bk[ni] = *reinterpret_cast<const bf16x8*>(R + 2560 + (ni*16 + l15)*40 + g*8);
    f32x4 s[2][4];
#pragma unroll
    for (int mi=0;mi<2;++mi)
#pragma unroll
        for (int ni=0;ni<4;++ni)
            s[mi][ni] = __builtin_amdgcn_mfma_f32_16x16x32_bf16(aq[mi], bk[ni], zero, 0,0,0);
    __syncthreads();                                  // (3) Q,K dead -> P overlay safe

    // ---- scale + (mask|bias), wave-parallel softmax, P -> R pitch 72 ----
    const float* addb = ADD + (size_t)(((wiC*3 + wjC)*8 + h) << 12);
    float rs[2][4];
#pragma unroll
    for (int mi=0;mi<2;++mi){
        const int qbase = r0 + mi*16 + g*4;
#pragma unroll
        for (int ni=0;ni<4;++ni){
            const int k = ni*16 + l15;
#pragma unroll
            for (int r=0;r<4;++r)
                s[mi][ni][r] = fmaf(s[mi][ni][r], SCALE_F, addb[((qbase + r) << 6) + k]);
        }
#pragma unroll
        for (int r=0;r<4;++r){
            float mx = fmaxf(fmaxf(s[mi][0][r], s[mi][1][r]), fmaxf(s[mi][2][r], s[mi][3][r]));
            mx = fmaxf(mx, __shfl_xor(mx, 1));
            mx = fmaxf(mx, __shfl_xor(mx, 2));
            mx = fmaxf(mx, __shfl_xor(mx, 4));
            mx = fmaxf(mx, __shfl_xor(mx, 8));
            float sum = 0.f;
#pragma unroll
            for (int ni=0;ni<4;++ni){
                float p = __expf(s[mi][ni][r] - mx);
                s[mi][ni][r] = p;
                sum += p;
            }
            sum += __shfl_xor(sum, 1);
            sum += __shfl_xor(sum, 2);
            sum += __shfl_xor(sum, 4);
            sum += __shfl_xor(sum, 8);
            rs[mi][r] = 1.f / sum;
            const int q = qbase + r;
#pragma unroll
            for (int ni=0;ni<4;++ni)
                R[q*72 + ni*16 + l15] = f2bs(s[mi][ni][r]);
        }
    }

    // ---- PV: o[32][32] = P(own rows) @ V(full, swizzled b128) ----
    f32x4 o[2][2];
#pragma unroll
    for (int mi=0;mi<2;++mi){ o[mi][0]=zero; o[mi][1]=zero; }
    {
        const int sw = (l15 & 7) << 3;
#pragma unroll
        for (int ks=0;ks<2;++ks){
            bf16x8 pa[2], vb[2];
#pragma unroll
            for (int mi=0;mi<2;++mi)
                pa[mi] = *reinterpret_cast<const bf16x8*>(R + (r0 + mi*16 + l15)*72 + ks*32 + g*8);
#pragma unroll
            for (int nj=0;nj<2;++nj)
                vb[nj] = *reinterpret_cast<const bf16x8*>(VL + (((nj*16 + l15)*64 + ks*32 + g*8) ^ sw));
#pragma unroll
            for (int mi=0;mi<2;++mi)
#pragma unroll
                for (int nj=0;nj<2;++nj)
                    o[mi][nj] = __builtin_amdgcn_mfma_f32_16x16x32_bf16(pa[mi], vb[nj], o[mi][nj], 0,0,0);
        }
    }
    __syncthreads();                                  // (4) P dead -> att overlay safe

    // ---- att (normalized bf16) -> R pitch 40 ----
#pragma unroll
    for (int mi=0;mi<2;++mi)
#pragma unroll
        for (int nj=0;nj<2;++nj)
#pragma unroll
            for (int r=0;r<4;++r)
                R[(r0 + mi*16 + g*4 + r)*40 + nj*16 + l15] = f2bs(o[mi][nj][r] * rs[mi][r]);
    __syncthreads();                                  // (5) att visible to all

    // ---- O-GEMM: rows r0..r0+31, cols c0..c0+31 ----
    {
        bf16x8 wf[8][2];
#pragma unroll
        for (int kt=0;kt<8;++kt)
#pragma unroll
            for (int nj=0;nj<2;++nj)
                wf[kt][nj] = *reinterpret_cast<const bf16x8*>(Wot + (size_t)(c0 + nj*16 + l15)*256 + kt*32 + g*8);
        f32x4 acc[2][2];
#pragma unroll
        for (int mi=0;mi<2;++mi){ acc[mi][0]=zero; acc[mi][1]=zero; }
#pragma unroll
        for (int kt=0;kt<8;++kt){
            const short* areg = lds + WB + kt*WSZ;   // head kt's att
            bf16x8 af[2];
#pragma unroll
            for (int mi=0;mi<2;++mi)
                af[mi] = *reinterpret_cast<const bf16x8*>(areg + (r0 + mi*16 + l15)*40 + g*8);
#pragma unroll
            for (int mi=0;mi<2;++mi)
#pragma unroll
                for (int nj=0;nj<2;++nj)
                    acc[mi][nj] = __builtin_amdgcn_mfma_f32_16x16x32_bf16(af[mi], wf[kt][nj], acc[mi][nj], 0,0,0);
        }
#pragma unroll
        for (int nj=0;nj<2;++nj){
            const int col = c0 + nj*16 + l15;
            const float bv = bo[col];
#pragma unroll
            for (int mi=0;mi<2;++mi)
#pragma unroll
                for (int r=0;r<4;++r){
                    const int p = r0 + mi*16 + g*4 + r;
                    const int pr = ((wi << 3) + (p >> 3) + 4) & 127;
                    const int pc = ((wj << 3) + (p & 7) + 4) & 127;
                    const size_t gp = ((((size_t)b << 7) | pr) << 7) | pc;
                    out[gp * 256 + col] = acc[mi][nj][r] + bv;
                }
        }
    }
}

extern "C" void kernel_launch(void* const* d_in, const int* in_sizes, int n_in,
                              void* d_out, int out_size, void* d_ws, size_t ws_size,
                              hipStream_t stream) {
    const float* x    = (const float*)d_in[0];
    const float* z    = (const float*)d_in[1];
    const float* Wq   = (const float*)d_in[2];
    const float* bq   = (const float*)d_in[3];
    const float* Wkv  = (const float*)d_in[4];
    const float* bkv  = (const float*)d_in[5];
    const float* Wo   = (const float*)d_in[6];
    const float* bo   = (const float*)d_in[7];
    const float* rel  = (const float*)d_in[8];

    char* ws = (char*)d_ws;
    short* Wqt  = (short*)(ws);                    // 128 KiB
    short* Wkvt = (short*)(ws + 131072);           // 256 KiB
    short* Wot  = (short*)(ws + 393216);           // 128 KiB
    float* ADD  = (float*)(ws + 524288);           // 1.125 MiB

    prep_k<<<2176, 256, 0, stream>>>(Wq, Wkv, Wo, rel, Wqt, Wkvt, Wot, ADD);
    fused_k<<<2048, 1024, 0, stream>>>(x, z, Wqt, Wkvt, Wot, bq, bkv, bo, ADD, (float*)d_out);
}

// Round 8
// 274.066 us; speedup vs baseline: 1.2770x; 1.2770x over previous
//
#include <hip/hip_runtime.h>
#include <hip/hip_bf16.h>

// Swin shifted-window attention, MI355X gfx950 — split pipeline v3.
// B=8, H=W=128, D=256, NHEAD=8, DK=32, WS=8, NH=NW=16, WSQ=64, SHIFT=4.
// prep_k  : weight transposes (bf16) + fused (mask|rel-bias) ADD table.
// qkv_k   : 1 block = 1 window, 512 thr, LDS = x/z staging only (66 KB,
//           2 blocks/CU, no inner barriers). 1 head/wave -> Q,K,V windowed bf16
//           to global (V stored transposed [dk][pix]).
// attnO_k : 1 block = 1 window, 256 thr, 2 heads/wave. Q/K/V frags read
//           straight from global (L3-hot), softmax->P(LDS)->PV->att(LDS),
//           one barrier, in-block O-GEMM -> f32 out.

typedef __bf16  bf16x8 __attribute__((ext_vector_type(8)));
typedef short   short8 __attribute__((ext_vector_type(8)));
typedef short   short4v __attribute__((ext_vector_type(4)));
typedef float   f32x4  __attribute__((ext_vector_type(4)));

#define SCALE_F 0.17677669529663687f

__device__ __forceinline__ short f2bs(float f){
    __hip_bfloat16 h = __float2bfloat16(f);
    return __builtin_bit_cast(short, h);
}
__device__ __forceinline__ short8 cvt8(float4 a, float4 b){
    short8 t;
    t[0]=f2bs(a.x); t[1]=f2bs(a.y); t[2]=f2bs(a.z); t[3]=f2bs(a.w);
    t[4]=f2bs(b.x); t[5]=f2bs(b.y); t[6]=f2bs(b.z); t[7]=f2bs(b.w);
    return t;
}
__device__ __forceinline__ int strip3(int r, int c){
    if (c == 0) return 0;
    if (c == 1) return (r < 4) ? 0 : 1;
    return (r < 4) ? 2 : 0;
}

// ---------------- prep: weight transpose->bf16 + ADD table ------------------
__global__ __launch_bounds__(256) void prep_k(const float* __restrict__ Wq,
                                              const float* __restrict__ Wkv,
                                              const float* __restrict__ Wo,
                                              const float* __restrict__ rel,
                                              short* __restrict__ Wqt,
                                              short* __restrict__ Wkvt,
                                              short* __restrict__ Wot,
                                              float* __restrict__ ADD){
    int i = blockIdx.x * 256 + threadIdx.x;
    if (i < 65536){
        int n = i >> 8, k = i & 255;
        Wqt[i] = f2bs(Wq[k * 256 + n]);
    } else if (i < 196608){
        int j = i - 65536;
        int n = j >> 8, k = j & 255;
        Wkvt[j] = f2bs(Wkv[k * 512 + n]);
    } else if (i < 262144){
        int j = i - 196608;
        int n = j >> 8, k = j & 255;
        Wot[j] = f2bs(Wo[k * 256 + n]);
    } else {
        int j = i - 262144;
        int k = j & 63, q = (j >> 6) & 63, head = (j >> 12) & 7, cls = j >> 15;
        int wiC = cls / 3, wjC = cls - wiC * 3;
        int qr = q >> 3, qc = q & 7, kr = k >> 3, kc = k & 7;
        int lq = strip3(qr, wiC) * 3 + strip3(qc, wjC);
        int lk = strip3(kr, wiC) * 3 + strip3(kc, wjC);
        float pe = rel[((qr - kr + 7) * 15 + (qc - kc + 7)) * 8 + head];
        ADD[j] = (lq != lk) ? -1e9f : pe;
    }
}

// ---------------- k1: QKV projection, windowed outputs ----------------------
__global__ __launch_bounds__(512, 2) void qkv_k(
    const float* __restrict__ x, const float* __restrict__ z,
    const short* __restrict__ Wqt, const short* __restrict__ Wkvt,
    const float* __restrict__ bq, const float* __restrict__ bkv,
    short* __restrict__ Qw, short* __restrict__ Kw, short* __restrict__ Vw){
    __shared__ __align__(16) short lds[2 * 16896];   // xs, zs [64][264]
    const int tid = threadIdx.x, w = tid >> 6, lane = tid & 63;
    const int l15 = lane & 15, g = lane >> 4;
    const int bx = blockIdx.x;
    const int wj = bx & 15, wi = (bx >> 4) & 15, b = bx >> 8;
    const f32x4 zero = {0.f,0.f,0.f,0.f};

    // stage x,z windows -> LDS bf16 [64][264]
#pragma unroll
    for (int i=0;i<4;++i){
        const int u = tid + i*512;
        const int p = u >> 5, c8 = u & 31;
        const int pr = ((wi << 3) + (p >> 3) + 4) & 127;
        const int pc = ((wj << 3) + (p & 7) + 4) & 127;
        const size_t gidx = ((((((size_t)b << 7) | pr) << 7) | pc) << 8) + c8*8;
        const float4* xp = reinterpret_cast<const float4*>(x + gidx);
        float4 a0 = xp[0], a1 = xp[1];
        *reinterpret_cast<short8*>(lds + p*264 + c8*8) = cvt8(a0, a1);
        const float4* zp = reinterpret_cast<const float4*>(z + gidx);
        float4 b0 = zp[0], b1 = zp[1];
        *reinterpret_cast<short8*>(lds + 16896 + p*264 + c8*8) = cvt8(b0, b1);
    }
    __syncthreads();

    const int c0 = w * 32;
    const size_t base = ((((size_t)b*8 + w)*16 + wi)*16 + wj) * 2048;

    // ---- Q projection ----
    {
        f32x4 acc[4][2];
#pragma unroll
        for (int mi=0;mi<4;++mi){ acc[mi][0]=zero; acc[mi][1]=zero; }
#pragma unroll
        for (int kt=0;kt<8;++kt){
            bf16x8 af[4], wf[2];
#pragma unroll
            for (int nj=0;nj<2;++nj)
                wf[nj] = *reinterpret_cast<const bf16x8*>(Wqt + (size_t)(c0 + nj*16 + l15)*256 + kt*32 + g*8);
#pragma unroll
            for (int mi=0;mi<4;++mi)
                af[mi] = *reinterpret_cast<const bf16x8*>(lds + (mi*16 + l15)*264 + kt*32 + g*8);
#pragma unroll
            for (int mi=0;mi<4;++mi)
#pragma unroll
                for (int nj=0;nj<2;++nj)
                    acc[mi][nj] = __builtin_amdgcn_mfma_f32_16x16x32_bf16(af[mi], wf[nj], acc[mi][nj], 0,0,0);
        }
#pragma unroll
        for (int nj=0;nj<2;++nj){
            float bv = bq[c0 + nj*16 + l15];
#pragma unroll
            for (int mi=0;mi<4;++mi)
#pragma unroll
                for (int r=0;r<4;++r)
                    Qw[base + (size_t)(mi*16 + g*4 + r)*32 + nj*16 + l15] = f2bs(acc[mi][nj][r] + bv);
        }
    }
    // ---- K projection ----
    {
        f32x4 acc[4][2];
#pragma unroll
        for (int mi=0;mi<4;++mi){ acc[mi][0]=zero; acc[mi][1]=zero; }
#pragma unroll
        for (int kt=0;kt<8;++kt){
            bf16x8 af[4], wf[2];
#pragma unroll
            for (int nj=0;nj<2;++nj)
                wf[nj] = *reinterpret_cast<const bf16x8*>(Wkvt + (size_t)(c0 + nj*16 + l15)*256 + kt*32 + g*8);
#pragma unroll
            for (int mi=0;mi<4;++mi)
                af[mi] = *reinterpret_cast<const bf16x8*>(lds + 16896 + (mi*16 + l15)*264 + kt*32 + g*8);
#pragma unroll
            for (int mi=0;mi<4;++mi)
#pragma unroll
                for (int nj=0;nj<2;++nj)
                    acc[mi][nj] = __builtin_amdgcn_mfma_f32_16x16x32_bf16(af[mi], wf[nj], acc[mi][nj], 0,0,0);
        }
#pragma unroll
        for (int nj=0;nj<2;++nj){
            float bv = bkv[c0 + nj*16 + l15];
#pragma unroll
            for (int mi=0;mi<4;++mi)
#pragma unroll
                for (int r=0;r<4;++r)
                    Kw[base + (size_t)(mi*16 + g*4 + r)*32 + nj*16 + l15] = f2bs(acc[mi][nj][r] + bv);
        }
    }
    // ---- V projection (store transposed [dk][pix], 8B vector stores) ----
    {
        f32x4 acc[4][2];
#pragma unroll
        for (int mi=0;mi<4;++mi){ acc[mi][0]=zero; acc[mi][1]=zero; }
#pragma unroll
        for (int kt=0;kt<8;++kt){
            bf16x8 af[4], wf[2];
#pragma unroll
            for (int nj=0;nj<2;++nj)
                wf[nj] = *reinterpret_cast<const bf16x8*>(Wkvt + (size_t)(256 + c0 + nj*16 + l15)*256 + kt*32 + g*8);
#pragma unroll
            for (int mi=0;mi<4;++mi)
                af[mi] = *reinterpret_cast<const bf16x8*>(lds + 16896 + (mi*16 + l15)*264 + kt*32 + g*8);
#pragma unroll
            for (int mi=0;mi<4;++mi)
#pragma unroll
                for (int nj=0;nj<2;++nj)
                    acc[mi][nj] = __builtin_amdgcn_mfma_f32_16x16x32_bf16(af[mi], wf[nj], acc[mi][nj], 0,0,0);
        }
#pragma unroll
        for (int nj=0;nj<2;++nj){
            float bv = bkv[256 + c0 + nj*16 + l15];
            const int dk = nj*16 + l15;
#pragma unroll
            for (int mi=0;mi<4;++mi){
                short4v t;
#pragma unroll
                for (int r=0;r<4;++r) t[r] = f2bs(acc[mi][nj][r] + bv);
                *reinterpret_cast<short4v*>(Vw + base + (size_t)dk*64 + mi*16 + g*4) = t;
            }
        }
    }
}

// ---------------- k2: attention + O-GEMM ------------------------------------
__global__ __launch_bounds__(256, 2) void attnO_k(
    const short* __restrict__ Qw, const short* __restrict__ Kw,
    const short* __restrict__ Vw, const short* __restrict__ Wot,
    const float* __restrict__ bo, const float* __restrict__ ADD,
    float* __restrict__ out){
    __shared__ __align__(16) short lds[4*4608 + 16896];  // 4x P[64][72] + att[64][264]
    const int tid = threadIdx.x, w = tid >> 6, lane = tid & 63;
    const int l15 = lane & 15, g = lane >> 4;
    const int bx = blockIdx.x;
    const int wj = bx & 15, wi = (bx >> 4) & 15, b = bx >> 8;
    const int wiC = (wi > 13) ? wi - 13 : 0;
    const int wjC = (wj > 13) ? wj - 13 : 0;
    short* P   = lds + w * 4608;
    short* att = lds + 18432;
    const f32x4 zero = {0.f,0.f,0.f,0.f};

    for (int hh = 0; hh < 2; ++hh){
        const int h = w + hh * 4;
        const size_t base = ((((size_t)b*8 + h)*16 + wi)*16 + wj) * 2048;

        // QK^T from global fragments
        bf16x8 aq[4], bk[4];
#pragma unroll
        for (int mi=0;mi<4;++mi)
            aq[mi] = *reinterpret_cast<const bf16x8*>(Qw + base + (size_t)(mi*16 + l15)*32 + g*8);
#pragma unroll
        for (int ni=0;ni<4;++ni)
            bk[ni] = *reinterpret_cast<const bf16x8*>(Kw + base + (size_t)(ni*16 + l15)*32 + g*8);
        f32x4 s[4][4];
#pragma unroll
        for (int mi=0;mi<4;++mi)
#pragma unroll
            for (int ni=0;ni<4;++ni)
                s[mi][ni] = __builtin_amdgcn_mfma_f32_16x16x32_bf16(aq[mi], bk[ni], zero, 0,0,0);

        // scale + (mask|bias), wave-parallel softmax, unnormalized P -> LDS p72
        const float* addb = ADD + (size_t)(((wiC*3 + wjC)*8 + h) << 12);
        float rs[4][4];
#pragma unroll
        for (int mi=0;mi<4;++mi){
            const int qbase = mi*16 + g*4;
#pragma unroll
            for (int ni=0;ni<4;++ni){
                const int k = ni*16 + l15;
#pragma unroll
                for (int r=0;r<4;++r)
                    s[mi][ni][r] = fmaf(s[mi][ni][r], SCALE_F, addb[((qbase + r) << 6) + k]);
            }
#pragma unroll
            for (int r=0;r<4;++r){
                float mx = fmaxf(fmaxf(s[mi][0][r], s[mi][1][r]), fmaxf(s[mi][2][r], s[mi][3][r]));
                mx = fmaxf(mx, __shfl_xor(mx, 1));
                mx = fmaxf(mx, __shfl_xor(mx, 2));
                mx = fmaxf(mx, __shfl_xor(mx, 4));
                mx = fmaxf(mx, __shfl_xor(mx, 8));
                float sum = 0.f;
#pragma unroll
                for (int ni=0;ni<4;++ni){
                    float p = __expf(s[mi][ni][r] - mx);
                    s[mi][ni][r] = p;
                    sum += p;
                }
                sum += __shfl_xor(sum, 1);
                sum += __shfl_xor(sum, 2);
                sum += __shfl_xor(sum, 4);
                sum += __shfl_xor(sum, 8);
                rs[mi][r] = 1.f / sum;
                const int q = qbase + r;
#pragma unroll
                for (int ni=0;ni<4;++ni)
                    P[q*72 + ni*16 + l15] = f2bs(s[mi][ni][r]);
            }
        }

        // PV: P from LDS, V^T fragments straight from global
        f32x4 o[4][2];
#pragma unroll
        for (int mi=0;mi<4;++mi){ o[mi][0]=zero; o[mi][1]=zero; }
#pragma unroll
        for (int ks=0;ks<2;++ks){
            bf16x8 pa[4], vb[2];
#pragma unroll
            for (int mi=0;mi<4;++mi)
                pa[mi] = *reinterpret_cast<const bf16x8*>(P + (mi*16 + l15)*72 + ks*32 + g*8);
#pragma unroll
            for (int nj=0;nj<2;++nj)
                vb[nj] = *reinterpret_cast<const bf16x8*>(Vw + base + (size_t)(nj*16 + l15)*64 + ks*32 + g*8);
#pragma unroll
            for (int mi=0;mi<4;++mi)
#pragma unroll
                for (int nj=0;nj<2;++nj)
                    o[mi][nj] = __builtin_amdgcn_mfma_f32_16x16x32_bf16(pa[mi], vb[nj], o[mi][nj], 0,0,0);
        }

        // normalized att (bf16) -> att LDS [pix][264], cols h*32..h*32+31
#pragma unroll
        for (int mi=0;mi<4;++mi)
#pragma unroll
            for (int nj=0;nj<2;++nj)
#pragma unroll
                for (int r=0;r<4;++r)
                    att[(mi*16 + g*4 + r)*264 + h*32 + nj*16 + l15] = f2bs(o[mi][nj][r] * rs[mi][r]);
    }
    __syncthreads();

    // ---- O-GEMM: out[64 pix][256] = att @ Wot^T + bo; wave w -> cols w*64.. ----
    f32x4 acc[4][4];
#pragma unroll
    for (int mi=0;mi<4;++mi)
#pragma unroll
        for (int nj=0;nj<4;++nj) acc[mi][nj] = zero;
#pragma unroll
    for (int kt=0;kt<8;++kt){
        bf16x8 af[4], bfm[4];
#pragma unroll
        for (int mi=0;mi<4;++mi)
            af[mi] = *reinterpret_cast<const bf16x8*>(att + (mi*16 + l15)*264 + kt*32 + g*8);
#pragma unroll
        for (int nj=0;nj<4;++nj)
            bfm[nj] = *reinterpret_cast<const bf16x8*>(Wot + (size_t)(w*64 + nj*16 + l15)*256 + kt*32 + g*8);
#pragma unroll
        for (int mi=0;mi<4;++mi)
#pragma unroll
            for (int nj=0;nj<4;++nj)
                acc[mi][nj] = __builtin_amdgcn_mfma_f32_16x16x32_bf16(af[mi], bfm[nj], acc[mi][nj], 0,0,0);
    }
#pragma unroll
    for (int nj=0;nj<4;++nj){
        const int col = w*64 + nj*16 + l15;
        const float bv = bo[col];
#pragma unroll
        for (int mi=0;mi<4;++mi)
#pragma unroll
            for (int r=0;r<4;++r){
                const int p = mi*16 + g*4 + r;
                const int pr = ((wi << 3) + (p >> 3) + 4) & 127;
                const int pc = ((wj << 3) + (p & 7) + 4) & 127;
                const size_t gp = ((((size_t)b << 7) | pr) << 7) | pc;
                out[gp * 256 + col] = acc[mi][nj][r] + bv;
            }
    }
}

extern "C" void kernel_launch(void* const* d_in, const int* in_sizes, int n_in,
                              void* d_out, int out_size, void* d_ws, size_t ws_size,
                              hipStream_t stream) {
    const float* x    = (const float*)d_in[0];
    const float* z    = (const float*)d_in[1];
    const float* Wq   = (const float*)d_in[2];
    const float* bq   = (const float*)d_in[3];
    const float* Wkv  = (const float*)d_in[4];
    const float* bkv  = (const float*)d_in[5];
    const float* Wo   = (const float*)d_in[6];
    const float* bo   = (const float*)d_in[7];
    const float* rel  = (const float*)d_in[8];

    char* ws = (char*)d_ws;
    short* Wqt  = (short*)(ws);                     // 128 KiB
    short* Wkvt = (short*)(ws + 131072);            // 256 KiB
    short* Wot  = (short*)(ws + 393216);            // 128 KiB
    float* ADD  = (float*)(ws + 524288);            // 1.125 MiB
    short* Qw   = (short*)(ws + 2097152);           // 64 MiB
    short* Kw   = (short*)(ws + 69206016);          // 64 MiB
    short* Vw   = (short*)(ws + 136314880);         // 64 MiB

    prep_k <<<2176, 256, 0, stream>>>(Wq, Wkv, Wo, rel, Wqt, Wkvt, Wot, ADD);
    qkv_k  <<<2048, 512, 0, stream>>>(x, z, Wqt, Wkvt, bq, bkv, Qw, Kw, Vw);
    attnO_k<<<2048, 256, 0, stream>>>(Qw, Kw, Vw, Wot, bo, ADD, (float*)d_out);
}